// Round 5
// baseline (445.484 us; speedup 1.0000x reference)
//
#include <hip/hip_runtime.h>

// QKV attention: qkv [B=64, 3*64, T=2048] fp32 -> out [64, 64, 2048] fp32.
// Round 12: split-K + LDS-traffic removal after r11 post-mortem.
//  - r11 lesson: BQ=128 doubled LDS traffic/FLOP, and 32-row same-column
//    fragment reads are irreducibly 4-way conflicted under any within-row
//    swizzle (8 slots, 32 rows). LDS was the busiest pipe (~47%+12% confl).
//  - Split-K: block = 256 queries x 1024 keys (16 tiles). Grid 1024 =
//    4 blocks/CU (r11 concurrency) at BQ=256 amortization (r10 economics).
//    No-max softmax => partials combine linearly: half0 -> out (unnorm),
//    half1 -> ws.O1, l -> ws.l; combine kernel does (O0+O1)/(l0+l1).
//  - K frags load DIRECTLY from prep'd global fp16 [s][c] (L2-hot, XCD
//    grouped): Ks staging + its 4-way reads deleted. LDS ops/tile halved.
//  - Vs granule-major layout [s>>3][c][s&7]: PV frag reads are contiguous
//    512B runs (stride-1 = conflict-free); staging stripe-schedulable.
//  - Compute core unchanged (verified r10/r11): 32x32 MFMA, S^T layout,
//    exp2 pre-folded scale, pkrtz + v_permlane32_swap_b32 in-reg P rebuild.
// NOTE: v_cvt_pk_bf16_f32 inline asm proven wrong on HW (r3/4/5) - banned.

#define DHEAD 64
#define TLEN  2048
#define NB    64
#define BQ    256
#define BK    64
#define HALF_S 1024
#define NT2   (HALF_S / BK)   // 16 tiles per block
#define LDT   65              // prep fp32 transpose leading dim

#define KT_BYTES (NB * DHEAD * TLEN * 2)           // 16.78 MB fp16 K^T
#define L_BYTES  (2 * NB * TLEN * 4)               // 1.05 MB fp32 l
// O1 fp32 33.55 MB follows; total ws = 51.4 MB.

typedef _Float16 h16x8 __attribute__((ext_vector_type(8)));
typedef _Float16 h16x2 __attribute__((ext_vector_type(2)));
typedef __fp16   fp16x2 __attribute__((ext_vector_type(2)));
typedef float    f32x16 __attribute__((ext_vector_type(16)));

// 1/sqrt(sqrt(64)) * sqrt(log2(e)): applied to Q and K; scores arrive
// pre-scaled for exp2.
#define QK_SCALE 0.42466090267246895f

extern "C" __device__ float __ocml_native_exp2_f32(float);

union H2U  { h16x2 h; fp16x2 f; unsigned u; };
union FRAG { h16x8 v; unsigned u[4]; };

__device__ __forceinline__ unsigned pk_u(float a, float b) {
    H2U x; x.f = __builtin_amdgcn_cvt_pkrtz(a, b); return x.u;   // v_cvt_pkrtz_f16_f32
}

// Vs granule-major physical index: elem (c, s) -> (s>>3)*512 + c*8 + (s&7).
// Fragment read (c varies per lane, s-granule fixed) = contiguous 512B run.
__device__ __forceinline__ int vidx(int c, int s) {
    return ((s >> 3) << 9) + (c << 3) + (s & 7);
}

// ---------- prep: K -> fp16 [b][s][c] (transposed, pre-scaled) ----------
__global__ __launch_bounds__(256)
void prep_k(const float* __restrict__ qkv, _Float16* __restrict__ ws) {
    __shared__ float T32[64 * LDT];
    const int tile = blockIdx.x, b = blockIdx.y;
    const int tid = threadIdx.x;
    const float* src = qkv + ((size_t)b * 3 + 1) * DHEAD * TLEN + tile * 64;
    _Float16* dst = ws + (size_t)b * DHEAD * TLEN + (size_t)tile * 64 * DHEAD;
    {
        int c = tid >> 4, t4 = (tid & 15) * 4;
        #pragma unroll
        for (int rr = 0; rr < 4; ++rr, c += 16) {
            float4 f = *(const float4*)(src + c * TLEN + t4);
            T32[(t4 + 0) * LDT + c] = f.x;
            T32[(t4 + 1) * LDT + c] = f.y;
            T32[(t4 + 2) * LDT + c] = f.z;
            T32[(t4 + 3) * LDT + c] = f.w;
        }
    }
    __syncthreads();
    #pragma unroll
    for (int rep = 0; rep < 2; ++rep) {
        int idx = rep * 256 + tid;
        int t = idx >> 3, j = idx & 7;
        const float* row = &T32[t * LDT + j * 8];
        FRAG o;
        o.u[0] = pk_u(row[0] * QK_SCALE, row[1] * QK_SCALE);
        o.u[1] = pk_u(row[2] * QK_SCALE, row[3] * QK_SCALE);
        o.u[2] = pk_u(row[4] * QK_SCALE, row[5] * QK_SCALE);
        o.u[3] = pk_u(row[6] * QK_SCALE, row[7] * QK_SCALE);
        *(h16x8*)(dst + t * DHEAD + j * 8) = o.v;
    }
}

// ---------- attention (split-K half) ----------
__global__ __launch_bounds__(256, 4)
void attn(const float* __restrict__ qkv, const _Float16* __restrict__ kt,
          float* __restrict__ lbuf, float* __restrict__ o1,
          float* __restrict__ out) {
    __shared__ alignas(16) _Float16 Vs[2][64 * 64];   // granule-major, dbuf

    const int tid  = threadIdx.x;
    const int wave = tid >> 6;
    const int lane = tid & 63;
    const int h    = lane >> 5;    // 32x32 MFMA half
    const int c32  = lane & 31;

    // bijective XCD swizzle over 1024 blocks: all 16 (half,qtile) blocks of
    // head b land on XCD b&7 (K fp16 + V fp32 of the head stay L2-hot).
    const int flat  = blockIdx.x;
    const int x     = flat & 7, y = flat >> 3;
    const int b     = ((y >> 4) << 3) | x;
    const int inner = y & 15;
    const int shalf = inner & 1;
    const int qt    = inner >> 1;
    const int t0    = qt * BQ + wave * 64;
    const int sbase = shalf * HALF_S;

    const float* qg = qkv + ((size_t)b * 3 + 0) * DHEAD * TLEN;
    const float* vg = qkv + ((size_t)b * 3 + 2) * DHEAD * TLEN;
    const _Float16* kbp = kt + (size_t)b * DHEAD * TLEN + (size_t)sbase * DHEAD;

    // ---- hoist Q B-frags: B[k=c][n=t], lane (h,c32) holds Q[t0+nb*32+c32][...]
    h16x8 qf[2][4];
    #pragma unroll
    for (int nb = 0; nb < 2; ++nb)
        #pragma unroll
        for (int kbq = 0; kbq < 4; ++kbq) {
            const float* qp = qg + (size_t)(kbq * 16 + h * 8) * TLEN + t0 + nb * 32 + c32;
            FRAG f;
            #pragma unroll
            for (int w = 0; w < 4; ++w)
                f.u[w] = pk_u(qp[(size_t)(2 * w) * TLEN] * QK_SCALE,
                              qp[(size_t)(2 * w + 1) * TLEN] * QK_SCALE);
            qf[nb][kbq] = f.v;
        }

    f32x16 acco[2][2];
    #pragma unroll
    for (int cb = 0; cb < 2; ++cb)
        #pragma unroll
        for (int nb = 0; nb < 2; ++nb)
            #pragma unroll
            for (int r = 0; r < 16; ++r) acco[cb][nb][r] = 0.f;
    float lp[2] = {0.f, 0.f};

    // V staging map: thread -> (c row 0..63, 16-wide s chunk)
    const int sr = tid >> 2;
    const int sq = (tid & 3) * 16;

    h16x8 vc2[2];
    auto PREF = [&](int s0) {
        const float* vp = vg + (size_t)sr * TLEN + sbase + s0 + sq;
        float4 v0 = *(const float4*)(vp + 0);
        float4 v1 = *(const float4*)(vp + 4);
        float4 v2 = *(const float4*)(vp + 8);
        float4 v3 = *(const float4*)(vp + 12);
        FRAG a, c;
        a.u[0] = pk_u(v0.x, v0.y); a.u[1] = pk_u(v0.z, v0.w);
        a.u[2] = pk_u(v1.x, v1.y); a.u[3] = pk_u(v1.z, v1.w);
        c.u[0] = pk_u(v2.x, v2.y); c.u[1] = pk_u(v2.z, v2.w);
        c.u[2] = pk_u(v3.x, v3.y); c.u[3] = pk_u(v3.z, v3.w);
        vc2[0] = a.v; vc2[1] = c.v;
    };

    PREF(0);

    for (int it = 0; it < NT2; ++it) {
        const int s0 = it * BK;

        // ---- K frags for this tile: direct global 16B loads (L2-hot).
        // Issue first; latency covered by staging + barrier + PREF issue.
        h16x8 kf[8];
        #pragma unroll
        for (int mb = 0; mb < 2; ++mb)
            #pragma unroll
            for (int kbq = 0; kbq < 4; ++kbq)
                kf[mb * 4 + kbq] = *(const h16x8*)(kbp + (size_t)(s0 + mb * 32 + c32) * DHEAD
                                                   + kbq * 16 + h * 8);

        _Float16* vsb = Vs[it & 1];
        // write tile it into buf[it&1]; last readers ran at tile it-2,
        // fenced by barrier of it-1 -> no pre-write barrier (r11 proven).
        *(h16x8*)&vsb[vidx(sr, sq)]     = vc2[0];
        *(h16x8*)&vsb[vidx(sr, sq + 8)] = vc2[1];
        __syncthreads();                        // publish tile it

        if (it + 1 < NT2) PREF((it + 1) * BK);  // in flight across compute

        #pragma unroll
        for (int mb = 0; mb < 2; ++mb) {
            // ---- S^T = K^T Q : D[m=s][n=t], lane holds rows (r&3)+8*(r>>2)+4h
            f32x16 accs[2];
            #pragma unroll
            for (int nb = 0; nb < 2; ++nb)
                #pragma unroll
                for (int r = 0; r < 16; ++r) accs[nb][r] = 0.f;

            __builtin_amdgcn_s_setprio(1);
            #pragma unroll
            for (int kbq = 0; kbq < 4; ++kbq) {
                h16x8 ka = kf[mb * 4 + kbq];
                accs[0] = __builtin_amdgcn_mfma_f32_32x32x16_f16(ka, qf[0][kbq], accs[0], 0, 0, 0);
                accs[1] = __builtin_amdgcn_mfma_f32_32x32x16_f16(ka, qf[1][kbq], accs[1], 0, 0, 0);
            }
            __builtin_amdgcn_s_setprio(0);

            // ---- softmax numerator (exp2, scale pre-folded) + in-register
            // B-frag rebuild: 8x pkrtz + 4x permlane32_swap per 32x32 block.
            h16x8 pb[2][2];   // [kb16][nb]
            #pragma unroll
            for (int nb = 0; nb < 2; ++nb) {
                float e[16];
                #pragma unroll
                for (int r = 0; r < 16; ++r) e[r] = __ocml_native_exp2_f32(accs[nb][r]);
                float s0v = 0.f;
                #pragma unroll
                for (int r = 0; r < 16; ++r) s0v += e[r];
                lp[nb] += s0v;
                #pragma unroll
                for (int kb16 = 0; kb16 < 2; ++kb16) {
                    const float* ee = e + kb16 * 8;
                    unsigned a01 = pk_u(ee[0], ee[1]);
                    unsigned a23 = pk_u(ee[2], ee[3]);
                    unsigned b01 = pk_u(ee[4], ee[5]);
                    unsigned b23 = pk_u(ee[6], ee[7]);
                    asm volatile("v_permlane32_swap_b32 %0, %1" : "+v"(a01), "+v"(b01));
                    asm volatile("v_permlane32_swap_b32 %0, %1" : "+v"(a23), "+v"(b23));
                    FRAG f;
                    f.u[0] = a01; f.u[1] = a23; f.u[2] = b01; f.u[3] = b23;
                    pb[kb16][nb] = f.v;
                }
            }

            // ---- O^T += V P^T : A = Vs granule-major rows (conflict-free),
            //      B = pb (registers, no LDS)
            __builtin_amdgcn_s_setprio(1);
            #pragma unroll
            for (int kb16 = 0; kb16 < 2; ++kb16) {
                const int scol = mb * 32 + kb16 * 16 + h * 8;
                #pragma unroll
                for (int cb = 0; cb < 2; ++cb) {
                    h16x8 va = *(const h16x8*)&vsb[vidx(cb * 32 + c32, scol)];
                    acco[cb][0] = __builtin_amdgcn_mfma_f32_32x32x16_f16(va, pb[kb16][0], acco[cb][0], 0, 0, 0);
                    acco[cb][1] = __builtin_amdgcn_mfma_f32_32x32x16_f16(va, pb[kb16][1], acco[cb][1], 0, 0, 0);
                }
            }
            __builtin_amdgcn_s_setprio(0);
        }
    }

    // ---- epilogue: UNNORMALIZED partial O^T + per-query l (split-K combine)
    float lsum[2];
    #pragma unroll
    for (int nb = 0; nb < 2; ++nb) {
        float l = lp[nb];
        l += __shfl_xor(l, 32);
        lsum[nb] = l;
    }

    float* op = (shalf == 0 ? out : o1) + (size_t)b * DHEAD * TLEN + t0;
    #pragma unroll
    for (int cb = 0; cb < 2; ++cb)
        #pragma unroll
        for (int nb = 0; nb < 2; ++nb)
            #pragma unroll
            for (int r = 0; r < 16; ++r) {
                const int c = cb * 32 + (r & 3) + 8 * (r >> 2) + 4 * h;
                op[(size_t)c * TLEN + nb * 32 + c32] = acco[cb][nb][r];
            }
    // lane = h*32+c32 covers query t0+lane; value = lsum[lane>>5]
    lbuf[(size_t)shalf * NB * TLEN + (size_t)b * TLEN + t0 + lane] = lsum[lane >> 5];
}

// ---------- combine: out = (O0 + O1) / (l0 + l1) ----------
__global__ __launch_bounds__(256)
void combine(float* __restrict__ out, const float* __restrict__ o1,
             const float* __restrict__ lbuf) {
    const size_t i = ((size_t)blockIdx.x * 256 + threadIdx.x) * 4;
    const int b = (int)(i >> 17);          // i / (64*2048)
    const int t = (int)(i & 2047);
    float4 a  = *(const float4*)(out + i);
    float4 c  = *(const float4*)(o1 + i);
    float4 l0 = *(const float4*)(lbuf + (size_t)b * TLEN + t);
    float4 l1 = *(const float4*)(lbuf + (size_t)NB * TLEN + (size_t)b * TLEN + t);
    float4 r;
    r.x = (a.x + c.x) / (l0.x + l1.x);
    r.y = (a.y + c.y) / (l0.y + l1.y);
    r.z = (a.z + c.z) / (l0.z + l1.z);
    r.w = (a.w + c.w) / (l0.w + l1.w);
    *(float4*)(out + i) = r;
}

extern "C" void kernel_launch(void* const* d_in, const int* in_sizes, int n_in,
                              void* d_out, int out_size, void* d_ws, size_t ws_size,
                              hipStream_t stream) {
    const float* qkv = (const float*)d_in[0];
    float* out = (float*)d_out;
    _Float16* kt = (_Float16*)d_ws;
    float* lbuf  = (float*)((char*)d_ws + KT_BYTES);
    float* o1    = (float*)((char*)d_ws + KT_BYTES + L_BYTES);
    // ws usage: 16.78 (Kt) + 1.05 (l) + 33.55 (O1) = 51.4 MB
    prep_k<<<dim3(TLEN / 64, NB), 256, 0, stream>>>(qkv, kt);
    attn<<<dim3(1024), 256, 0, stream>>>(qkv, kt, lbuf, o1, out);
    combine<<<dim3(NB * DHEAD * TLEN / 1024), 256, 0, stream>>>(out, o1, lbuf);
}

// Round 6
// 217.986 us; speedup vs baseline: 2.0436x; 2.0436x over previous
//
#include <hip/hip_runtime.h>

// QKV attention: qkv [B=64, 3*64, T=2048] fp32 -> out [64, 64, 2048] fp32.
// Round 13: r10 base (best verified: attn 104us, total 219.9us) + two
// mechanism-validated deltas. r12 post-mortem: direct-global K frag loads
// were a 16B/128B-stride gather (FETCH 41->638MB, MfmaUtil 8.7) -> frag
// reads MUST come from LDS; also wave64 ds_read_b128 floor is 8 clk, so
// r10's "4-way conflict" frag reads were already at the floor.
//  - Delta 1: K/V double-buffer, ONE barrier/tile (r11-proven mechanism)
//    at BQ=256 (r10 economics). LDS 32KB/block x 2 blocks/CU.
//  - Delta 2: intra-wave MFMA||VALU pipeline (T15): issue QK MFMAs for
//    BOTH 32-key halves first (accs[2][2]), then SM(0)->PV(0)->SM(1)->PV(1).
//    SM(0) exp2 chain overlaps half1's QK drain; SM(1) overlaps PV(0).
//    Occupancy is grid-limited (512 blocks = 2 waves/SIMD) so the extra
//    ~60 VGPR are free; __launch_bounds__(256,2).
//  - Compute core unchanged (verified r10/r11/r12): 32x32 MFMA, S^T layout,
//    exp2 pre-folded scale, pkrtz + v_permlane32_swap_b32 in-reg P rebuild,
//    prep_k for K transpose-convert.
// NOTE: v_cvt_pk_bf16_f32 inline asm proven wrong on HW (r3/4/5) - banned.

#define DHEAD 64
#define TLEN  2048
#define NB    64
#define BQ    256
#define BK    64
#define NT    (TLEN / BK)
#define LDT   65      // prep fp32 transpose leading dim

typedef _Float16 h16x8 __attribute__((ext_vector_type(8)));
typedef _Float16 h16x2 __attribute__((ext_vector_type(2)));
typedef __fp16   fp16x2 __attribute__((ext_vector_type(2)));
typedef float    f32x16 __attribute__((ext_vector_type(16)));

// 1/sqrt(sqrt(64)) * sqrt(log2(e)): applied to Q and K; scores arrive
// pre-scaled for exp2.
#define QK_SCALE 0.42466090267246895f

extern "C" __device__ float __ocml_native_exp2_f32(float);

union H2U  { h16x2 h; fp16x2 f; unsigned u; };
union FRAG { h16x8 v; unsigned u[4]; };

__device__ __forceinline__ unsigned pk_u(float a, float b) {
    H2U x; x.f = __builtin_amdgcn_cvt_pkrtz(a, b); return x.u;   // v_cvt_pkrtz_f16_f32
}

// fp16 tile [row][64]: 8-elem (16B) granule XOR swizzle keyed on row&7.
__device__ __forceinline__ int swz(int row, int col) {
    return row * 64 + (col ^ ((row & 7) << 3));
}

// ---------- prep: K -> fp16 [b][s][c] (transposed, pre-scaled) ----------
__global__ __launch_bounds__(256)
void prep_k(const float* __restrict__ qkv, _Float16* __restrict__ ws) {
    __shared__ float T32[64 * LDT];
    const int tile = blockIdx.x, b = blockIdx.y;
    const int tid = threadIdx.x;
    const float* src = qkv + ((size_t)b * 3 + 1) * DHEAD * TLEN + tile * 64;
    _Float16* dst = ws + (size_t)b * DHEAD * TLEN + (size_t)tile * 64 * DHEAD;
    {
        int c = tid >> 4, t4 = (tid & 15) * 4;
        #pragma unroll
        for (int rr = 0; rr < 4; ++rr, c += 16) {
            float4 f = *(const float4*)(src + c * TLEN + t4);
            T32[(t4 + 0) * LDT + c] = f.x;
            T32[(t4 + 1) * LDT + c] = f.y;
            T32[(t4 + 2) * LDT + c] = f.z;
            T32[(t4 + 3) * LDT + c] = f.w;
        }
    }
    __syncthreads();
    #pragma unroll
    for (int rep = 0; rep < 2; ++rep) {
        int idx = rep * 256 + tid;
        int t = idx >> 3, j = idx & 7;
        const float* row = &T32[t * LDT + j * 8];
        FRAG o;
        o.u[0] = pk_u(row[0] * QK_SCALE, row[1] * QK_SCALE);
        o.u[1] = pk_u(row[2] * QK_SCALE, row[3] * QK_SCALE);
        o.u[2] = pk_u(row[4] * QK_SCALE, row[5] * QK_SCALE);
        o.u[3] = pk_u(row[6] * QK_SCALE, row[7] * QK_SCALE);
        *(h16x8*)(dst + t * DHEAD + j * 8) = o.v;
    }
}

// ---------- attention ----------
__global__ __launch_bounds__(256, 2)
void attn(const float* __restrict__ qkv, const _Float16* __restrict__ kt,
          float* __restrict__ out) {
    __shared__ alignas(16) _Float16 Ks[2][64 * 64];   // fp16 K^T tile [s][c], swizzled
    __shared__ alignas(16) _Float16 Vs[2][64 * 64];   // fp16 V tile [c][s], swizzled

    const int tid  = threadIdx.x;
    const int wave = tid >> 6;
    const int lane = tid & 63;
    const int h    = lane >> 5;    // 32x32 MFMA half
    const int c32  = lane & 31;

    // bijective XCD swizzle: all 8 query-blocks of head b -> XCD (b&7).
    const int flat = blockIdx.x + (int)gridDim.x * blockIdx.y;  // gridDim.x = 8
    const int j8   = flat & 7, m8 = flat >> 3;
    const int b    = ((m8 & 7) << 3) | j8;
    const int t0   = (m8 >> 3) * BQ + wave * 64;

    const float* qg = qkv + ((size_t)b * 3 + 0) * DHEAD * TLEN;
    const float* vg = qkv + ((size_t)b * 3 + 2) * DHEAD * TLEN;
    const _Float16* kb = kt + (size_t)b * DHEAD * TLEN;

    // ---- hoist Q B-frags: B[k=c][n=t], lane (h,c32) holds Q[t0+nb*32+c32][kbq*16+h*8+j]
    h16x8 qf[2][4];
    #pragma unroll
    for (int nb = 0; nb < 2; ++nb)
        #pragma unroll
        for (int kbq = 0; kbq < 4; ++kbq) {
            const float* qp = qg + (size_t)(kbq * 16 + h * 8) * TLEN + t0 + nb * 32 + c32;
            FRAG f;
            #pragma unroll
            for (int w = 0; w < 4; ++w)
                f.u[w] = pk_u(qp[(size_t)(2 * w) * TLEN] * QK_SCALE,
                              qp[(size_t)(2 * w + 1) * TLEN] * QK_SCALE);
            qf[nb][kbq] = f.v;
        }

    f32x16 acco[2][2];
    #pragma unroll
    for (int cb = 0; cb < 2; ++cb)
        #pragma unroll
        for (int nb = 0; nb < 2; ++nb)
            #pragma unroll
            for (int r = 0; r < 16; ++r) acco[cb][nb][r] = 0.f;
    float lp[2] = {0.f, 0.f};

    // staging map: thread -> (row, 16-elem chunk). Same map for Ks and Vs.
    const int sr = tid >> 2;           // Ks: s row   | Vs: c row
    const int sq = (tid & 3) * 16;     // chunk base

    h16x8 kc2[2], vc2[2];

    auto PREF = [&](int s0) {
        const _Float16* kp = kb + (size_t)(s0 + sr) * DHEAD + sq;
        kc2[0] = *(const h16x8*)(kp);
        kc2[1] = *(const h16x8*)(kp + 8);
        const float* vp = vg + (size_t)sr * TLEN + s0 + sq;
        float4 v0 = *(const float4*)(vp + 0);
        float4 v1 = *(const float4*)(vp + 4);
        float4 v2 = *(const float4*)(vp + 8);
        float4 v3 = *(const float4*)(vp + 12);
        FRAG a, c;
        a.u[0] = pk_u(v0.x, v0.y); a.u[1] = pk_u(v0.z, v0.w);
        a.u[2] = pk_u(v1.x, v1.y); a.u[3] = pk_u(v1.z, v1.w);
        c.u[0] = pk_u(v2.x, v2.y); c.u[1] = pk_u(v2.z, v2.w);
        c.u[2] = pk_u(v3.x, v3.y); c.u[3] = pk_u(v3.z, v3.w);
        vc2[0] = a.v; vc2[1] = c.v;
    };

    PREF(0);

    for (int it = 0; it < NT; ++it) {
        _Float16* ksb = Ks[it & 1];
        _Float16* vsb = Vs[it & 1];
        // write tile it into buf[it&1]; its last readers ran at tile it-2,
        // fenced by the barrier of tile it-1 -> no pre-write barrier
        // (r11-proven: any wave here passed barrier(it-1), which postdates
        //  every wave's compute(it-2)).
        *(h16x8*)&ksb[swz(sr, sq)]     = kc2[0];
        *(h16x8*)&ksb[swz(sr, sq + 8)] = kc2[1];
        *(h16x8*)&vsb[swz(sr, sq)]     = vc2[0];
        *(h16x8*)&vsb[swz(sr, sq + 8)] = vc2[1];
        __syncthreads();                       // publish tile it

        if (it + 1 < NT) PREF((it + 1) * BK);  // in flight across compute

        // ---- QK phase for BOTH 32-key halves: S^T = K^T Q ----
        // D[m=s][n=t], lane holds rows (r&3)+8*(r>>2)+4h of its half.
        f32x16 accs[2][2];   // [mb][nb]
        #pragma unroll
        for (int mb = 0; mb < 2; ++mb)
            #pragma unroll
            for (int nb = 0; nb < 2; ++nb)
                #pragma unroll
                for (int r = 0; r < 16; ++r) accs[mb][nb][r] = 0.f;

        #pragma unroll
        for (int mb = 0; mb < 2; ++mb) {
            h16x8 ka[4];
            #pragma unroll
            for (int kbq = 0; kbq < 4; ++kbq)
                ka[kbq] = *(const h16x8*)&ksb[swz(mb * 32 + c32, kbq * 16 + h * 8)];
            __builtin_amdgcn_s_setprio(1);
            #pragma unroll
            for (int kbq = 0; kbq < 4; ++kbq) {
                accs[mb][0] = __builtin_amdgcn_mfma_f32_32x32x16_f16(ka[kbq], qf[0][kbq], accs[mb][0], 0, 0, 0);
                accs[mb][1] = __builtin_amdgcn_mfma_f32_32x32x16_f16(ka[kbq], qf[1][kbq], accs[mb][1], 0, 0, 0);
            }
            __builtin_amdgcn_s_setprio(0);
        }

        // ---- pipelined SM(0) -> PV(0) -> SM(1) -> PV(1) ----
        // SM(0)'s exp2 chain issues while mb=1's QK MFMAs drain;
        // SM(1) issues while PV(0)'s MFMAs drain.
        #pragma unroll
        for (int mb = 0; mb < 2; ++mb) {
            // pre-issue V frag reads for this half
            h16x8 va[2][2];   // [kb16][cb]
            #pragma unroll
            for (int kb16 = 0; kb16 < 2; ++kb16) {
                const int scol = mb * 32 + kb16 * 16 + h * 8;
                #pragma unroll
                for (int cb = 0; cb < 2; ++cb)
                    va[kb16][cb] = *(const h16x8*)&vsb[swz(cb * 32 + c32, scol)];
            }

            // softmax numerator (exp2, scale pre-folded) + in-register
            // B-frag rebuild: 8x pkrtz + 4x permlane32_swap per 32x32 block.
            h16x8 pb[2][2];   // [kb16][nb]
            #pragma unroll
            for (int nb = 0; nb < 2; ++nb) {
                float e[16];
                #pragma unroll
                for (int r = 0; r < 16; ++r) e[r] = __ocml_native_exp2_f32(accs[mb][nb][r]);
                float s0v = 0.f;
                #pragma unroll
                for (int r = 0; r < 16; ++r) s0v += e[r];
                lp[nb] += s0v;
                #pragma unroll
                for (int kb16 = 0; kb16 < 2; ++kb16) {
                    const float* ee = e + kb16 * 8;
                    unsigned a01 = pk_u(ee[0], ee[1]);
                    unsigned a23 = pk_u(ee[2], ee[3]);
                    unsigned b01 = pk_u(ee[4], ee[5]);
                    unsigned b23 = pk_u(ee[6], ee[7]);
                    asm volatile("v_permlane32_swap_b32 %0, %1" : "+v"(a01), "+v"(b01));
                    asm volatile("v_permlane32_swap_b32 %0, %1" : "+v"(a23), "+v"(b23));
                    FRAG f;
                    f.u[0] = a01; f.u[1] = a23; f.u[2] = b01; f.u[3] = b23;
                    pb[kb16][nb] = f.v;
                }
            }

            // O^T += V P^T : A = Vs rows (preloaded), B = pb (registers)
            __builtin_amdgcn_s_setprio(1);
            #pragma unroll
            for (int kb16 = 0; kb16 < 2; ++kb16)
                #pragma unroll
                for (int cb = 0; cb < 2; ++cb) {
                    acco[cb][0] = __builtin_amdgcn_mfma_f32_32x32x16_f16(va[kb16][cb], pb[kb16][0], acco[cb][0], 0, 0, 0);
                    acco[cb][1] = __builtin_amdgcn_mfma_f32_32x32x16_f16(va[kb16][cb], pb[kb16][1], acco[cb][1], 0, 0, 0);
                }
            __builtin_amdgcn_s_setprio(0);
        }
    }

    // ---- finalize: lane h and h^1 (xor 32) hold complementary s-rows
    float rinv[2];
    #pragma unroll
    for (int nb = 0; nb < 2; ++nb) {
        float l = lp[nb];
        l += __shfl_xor(l, 32);
        rinv[nb] = 1.0f / l;
    }

    float* ob = out + (size_t)b * DHEAD * TLEN + t0;
    #pragma unroll
    for (int cb = 0; cb < 2; ++cb)
        #pragma unroll
        for (int nb = 0; nb < 2; ++nb)
            #pragma unroll
            for (int r = 0; r < 16; ++r) {
                const int c = cb * 32 + (r & 3) + 8 * (r >> 2) + 4 * h;
                ob[(size_t)c * TLEN + nb * 32 + c32] = acco[cb][nb][r] * rinv[nb];
            }
}

extern "C" void kernel_launch(void* const* d_in, const int* in_sizes, int n_in,
                              void* d_out, int out_size, void* d_ws, size_t ws_size,
                              hipStream_t stream) {
    const float* qkv = (const float*)d_in[0];
    _Float16* ws = (_Float16*)d_ws;   // Kt: 64*64*2048*2 B = 16.8 MB
    float* out = (float*)d_out;
    prep_k<<<dim3(TLEN / 64, NB), 256, 0, stream>>>(qkv, ws);
    attn<<<dim3(TLEN / BQ, NB), 256, 0, stream>>>(qkv, ws, out);
}